// Round 1
// baseline (576.270 us; speedup 1.0000x reference)
//
#include <hip/hip_runtime.h>

// VFE fused kernel.
// B=32768 voxels, P=32 points, IN=7, D2=64, OUT=128 channels per point.
// local_f[b,p,d] = sum_k x[b,p,k]*W[d,k] + bias[d]
// global_f[b,g]  = max over flat local_f[b] range [g*32, g*32+32)   (view-reshape max!)
// out flat [b, p, c]: c<64 -> local_f[b,p,c]; c>=64 -> global_f[b, c-64]

#define B_VOX 32768
#define P_PTS 32
#define IN_F  7
#define D2_F  64

__global__ __launch_bounds__(256) void vfe_kernel(
    const float* __restrict__ x,
    const float* __restrict__ W,
    const float* __restrict__ bias,
    float* __restrict__ out)
{
    __shared__ float sW[D2_F * IN_F];            // 448
    __shared__ float sb[D2_F];                   // 64
    __shared__ float sx[P_PTS * IN_F];           // 224
    // slocal: words [0, 2048) ; sglob: words [2048, 2112)
    __shared__ alignas(16) float slds[P_PTS * D2_F + D2_F];

    const int t  = threadIdx.x;          // 0..255
    const int b  = blockIdx.x;           // voxel id

    // ---- stage W, bias, x[b] into LDS ----
    for (int i = t; i < D2_F * IN_F; i += 256) sW[i] = W[i];
    if (t < D2_F) sb[t] = bias[t];
    {
        const float* xb = x + (size_t)b * (P_PTS * IN_F);
        if (t < P_PTS * IN_F) sx[t] = xb[t];
    }
    __syncthreads();

    const int lane = t & 63;
    const int wv   = t >> 6;             // wave id 0..3
    const int half = lane >> 5;          // 0/1: which 32-lane half

    // ---- compute local_f (strided: iter s covers flat [256s + t]) ----
    // flat = t + 256 s  ->  p = flat>>6 = 4s + wv (wave-uniform), d = lane.
    // The 32 lanes of each half-wave hold exactly one global-max group.
    #pragma unroll
    for (int s = 0; s < 8; ++s) {
        const int p = 4 * s + wv;
        const int d = lane;
        float acc = sb[d];
        #pragma unroll
        for (int k = 0; k < IN_F; ++k)
            acc = fmaf(sx[p * IN_F + k], sW[d * IN_F + k], acc);
        slds[t + 256 * s] = acc;         // conflict-free: consecutive lanes, consecutive words

        // max over the 32-lane half-wave (stays inside the half: offsets <32)
        float m = acc;
        #pragma unroll
        for (int off = 16; off >= 1; off >>= 1)
            m = fmaxf(m, __shfl_xor(m, off, 64));
        if ((lane & 31) == 0)
            slds[2048 + 8 * s + 2 * wv + half] = m;   // sglob[d_g], d_g = flat/32
    }
    __syncthreads();

    // ---- coalesced epilogue: thread t writes float4 at word 4t + 1024s ----
    float4* out4 = (float4*)(out + (size_t)b * (P_PTS * 2 * D2_F));
    #pragma unroll
    for (int s = 0; s < 4; ++s) {
        const int idx = t + 256 * s;     // float4 index in [0,1024)
        const int o   = 4 * idx;         // word offset in voxel output
        const int c   = o & 127;         // channel (multiple of 4)
        const int p   = o >> 7;          // point
        const int a   = (c < 64) ? (p * 64 + c) : (2048 + (c - 64));  // branchless LDS select
        const float4 v = *(const float4*)&slds[a];
        out4[idx] = v;                   // lanes 0..63 cover 1 KiB contiguous
    }
}

extern "C" void kernel_launch(void* const* d_in, const int* in_sizes, int n_in,
                              void* d_out, int out_size, void* d_ws, size_t ws_size,
                              hipStream_t stream) {
    const float* x    = (const float*)d_in[0];   // [32768, 32, 7]
    const float* W    = (const float*)d_in[1];   // [64, 7]
    const float* bias = (const float*)d_in[2];   // [64]
    float* out        = (float*)d_out;           // [32768, 128, 32] flat

    vfe_kernel<<<B_VOX, 256, 0, stream>>>(x, W, bias, out);
}

// Round 2
// 547.310 us; speedup vs baseline: 1.0529x; 1.0529x over previous
//
#include <hip/hip_runtime.h>

// VFE fused kernel, round 2: cut LDS-pipe instruction count.
// B=32768 voxels, P=32 points, IN=7, D2=64, OUT=128 channels per point.
// local_f[b,p,d] = sum_k x[b,p,k]*W[d,k] + bias[d]
// global_f[b,g]  = max over flat local_f[b] range [g*32, g*32+32)   (view-reshape max)
// out flat [b,p,c]: c<64 -> local_f[b,p,c]; c>=64 -> global_f[b,c-64]
//
// Changes vs round 1 (kernel ~220us vs ~90us store floor, LDS/issue-bound):
//  - W row + bias per thread (d = lane fixed) loaded ONCE from global (L1-hot),
//    removing 56 ds_read_b32/thread.
//  - x staged into LDS padded to 8 floats/row -> 2 broadcast ds_read_b128 per
//    s-iter instead of 7 ds_read_b32 (56 -> 16 LDS ops/thread).
//  - wave wv owns rows p = 8wv..8wv+7; group id = 16wv+2s+half.

#define B_VOX 32768
#define P_PTS 32
#define IN_F  7
#define D2_F  64

__global__ __launch_bounds__(256) void vfe_kernel(
    const float* __restrict__ x,
    const float* __restrict__ W,
    const float* __restrict__ bias,
    float* __restrict__ out)
{
    __shared__ alignas(16) float sxp[P_PTS * 8];           // x rows padded 7->8
    __shared__ alignas(16) float slds[P_PTS * D2_F + D2_F]; // locals [0,2048) + globals [2048,2112)

    const int t    = threadIdx.x;        // 0..255
    const int b    = blockIdx.x;         // voxel id
    const int lane = t & 63;
    const int wv   = t >> 6;             // wave id 0..3

    // ---- stage x[b] (224 floats) into padded LDS, coalesced global read ----
    const float* xb = x + (size_t)b * (P_PTS * IN_F);
    if (t < P_PTS * IN_F) {
        const int p = t / IN_F;          // magic-mul division
        const int k = t - p * IN_F;
        sxp[p * 8 + k] = xb[t];
    }

    // ---- W row for d = lane + bias into registers (block-invariant, L1-hot) ----
    const float* Wr = W + lane * IN_F;
    const float w0 = Wr[0], w1 = Wr[1], w2 = Wr[2], w3 = Wr[3];
    const float w4 = Wr[4], w5 = Wr[5], w6 = Wr[6];
    const float bl = bias[lane];

    __syncthreads();

    const int half = lane >> 5;          // 0/1

    // ---- compute: wave wv handles rows p = 8wv + s, s = 0..7 ----
    #pragma unroll
    for (int s = 0; s < 8; ++s) {
        const int p = 8 * wv + s;
        const float4 lo = *(const float4*)&sxp[p * 8];       // wave-uniform broadcast
        const float4 hi = *(const float4*)&sxp[p * 8 + 4];
        float acc = bl;
        acc = fmaf(lo.x, w0, acc);
        acc = fmaf(lo.y, w1, acc);
        acc = fmaf(lo.z, w2, acc);
        acc = fmaf(lo.w, w3, acc);
        acc = fmaf(hi.x, w4, acc);
        acc = fmaf(hi.y, w5, acc);
        acc = fmaf(hi.z, w6, acc);
        slds[p * D2_F + lane] = acc;     // consecutive lanes, consecutive words

        // max over each 32-lane half (group g = 2p + half)
        float m = acc;
        m = fmaxf(m, __shfl_xor(m, 16, 64));
        m = fmaxf(m, __shfl_xor(m,  8, 64));
        m = fmaxf(m, __shfl_xor(m,  4, 64));
        m = fmaxf(m, __shfl_xor(m,  2, 64));
        m = fmaxf(m, __shfl_xor(m,  1, 64));
        if ((lane & 31) == 0)
            slds[2048 + 16 * wv + 2 * s + half] = m;
    }
    __syncthreads();

    // ---- coalesced epilogue: thread t writes float4 at word 4t + 1024s ----
    float4* out4 = (float4*)(out + (size_t)b * (P_PTS * 2 * D2_F));
    #pragma unroll
    for (int s = 0; s < 4; ++s) {
        const int idx = t + 256 * s;     // float4 index in [0,1024)
        const int o   = 4 * idx;         // word offset in voxel output
        const int c   = o & 127;         // channel (multiple of 4)
        const int p   = o >> 7;          // point
        const int a   = (c < 64) ? (p * 64 + c) : (2048 + (c - 64));
        const float4 v = *(const float4*)&slds[a];
        out4[idx] = v;                   // 64 lanes cover 1 KiB contiguous
    }
}

extern "C" void kernel_launch(void* const* d_in, const int* in_sizes, int n_in,
                              void* d_out, int out_size, void* d_ws, size_t ws_size,
                              hipStream_t stream) {
    const float* x    = (const float*)d_in[0];   // [32768, 32, 7]
    const float* W    = (const float*)d_in[1];   // [64, 7]
    const float* bias = (const float*)d_in[2];   // [64]
    float* out        = (float*)d_out;           // [32768, 128, 32] flat

    vfe_kernel<<<B_VOX, 256, 0, stream>>>(x, W, bias, out);
}